// Round 4
// baseline (571.127 us; speedup 1.0000x reference)
//
#include <hip/hip_runtime.h>
#include <hip/hip_bf16.h>

#define NN 100000
#define NE 1600000
#define FF 128
#define HH 128
#define CC 10
#define GG 64

typedef __attribute__((ext_vector_type(8))) short short8;
typedef __attribute__((ext_vector_type(8))) unsigned short ushort8;
typedef __attribute__((ext_vector_type(4))) float f32x4;

__device__ inline float bf2f(unsigned short u) {
    union { unsigned int i; float f; } x;
    x.i = ((unsigned int)u) << 16;
    return x.f;
}
__device__ inline unsigned short f2bf(float f) {
    union { float f; unsigned int i; } x;
    x.f = f;
    unsigned int r = x.i + 0x7FFF + ((x.i >> 16) & 1);  // RNE
    return (unsigned short)(r >> 16);
}

// ---------------- f32 -> bf16 bulk convert (8 elems/thread) ----------------
__global__ __launch_bounds__(256) void f2bf_kernel(const float* __restrict__ x,
                                                   unsigned short* __restrict__ xb) {
    int i = blockIdx.x * blockDim.x + threadIdx.x;
    if (i >= NN * HH / 8) return;
    float4 v0 = ((const float4*)x)[i * 2];
    float4 v1 = ((const float4*)x)[i * 2 + 1];
    ushort8 o;
    o[0] = f2bf(v0.x); o[1] = f2bf(v0.y); o[2] = f2bf(v0.z); o[3] = f2bf(v0.w);
    o[4] = f2bf(v1.x); o[5] = f2bf(v1.y); o[6] = f2bf(v1.z); o[7] = f2bf(v1.w);
    ((ushort8*)xb)[i] = o;
}

// ---------------- weight combine + pack into MFMA B-fragment order (bf16) ----
// Wpack layout per layer: [(cb*4+kb)*512 + lane*8 + j] = Wc[k][c],
//   k = kb*32 + (lane>>4)*8 + j,  c = cb*16 + (lane&15)
__global__ void combw_kernel(const float* __restrict__ W1, const float* __restrict__ b1,
                             const float* __restrict__ Wr1, const float* __restrict__ br1,
                             const float* __restrict__ W2, const float* __restrict__ b2,
                             const float* __restrict__ Wr, const float* __restrict__ br,
                             unsigned short* __restrict__ Wpack, float* __restrict__ bc) {
    int idx = blockIdx.x * blockDim.x + threadIdx.x;
    if (idx >= 3 * 16384) return;
    int l = idx / 16384, rem = idx % 16384;
    int cb = rem / 2048;
    int kb = (rem / 512) % 4;
    int lane = (rem / 8) % 64;
    int j = rem % 8;
    int k = kb * 32 + (lane >> 4) * 8 + j;
    int c = cb * 16 + (lane & 15);
    int wi = k * HH + c;
    float v = (l == 0) ? 0.95f * W1[wi] + 0.05f * Wr1[wi]
                       : 0.95f * W2[(l - 1) * 16384 + wi] + 0.05f * Wr[wi];
    Wpack[idx] = f2bf(v);
    if (rem < HH) {
        bc[l * HH + rem] = (l == 0) ? 0.95f * b1[rem] + 0.05f * br1[rem]
                                    : 0.95f * b2[(l - 1) * HH + rem] + 0.05f * br[rem];
    }
}

// ---------------- degree histogram over dst ----------------
__global__ void hist_kernel(const int* __restrict__ ei, int* __restrict__ cnt) {
    int stride = gridDim.x * blockDim.x;
    for (int e = blockIdx.x * blockDim.x + threadIdx.x; e < NE; e += stride)
        atomicAdd(&cnt[ei[NE + e]], 1);   // dst = ei[E + e]
}

__global__ void deg_kernel(const int* __restrict__ cnt, float* __restrict__ dinv,
                           float* __restrict__ selfn) {
    int stride = gridDim.x * blockDim.x;
    for (int n = blockIdx.x * blockDim.x + threadIdx.x; n < NN; n += stride) {
        float dg = (float)cnt[n] + 1.0f;
        dinv[n] = rsqrtf(dg);
        selfn[n] = 1.0f / dg;
    }
}

// ---------------- 3-kernel exclusive scan of cnt -> offs ----------------
__global__ __launch_bounds__(256) void scan1_kernel(const int* __restrict__ cnt, int* __restrict__ bsum) {
    __shared__ int sh[256];
    int b = blockIdx.x, t = threadIdx.x;
    int base = b * 1024 + t * 4;
    int s = 0;
#pragma unroll
    for (int j = 0; j < 4; ++j) { int i = base + j; if (i < NN) s += cnt[i]; }
    sh[t] = s; __syncthreads();
    for (int off = 128; off; off >>= 1) { if (t < off) sh[t] += sh[t + off]; __syncthreads(); }
    if (t == 0) bsum[b] = sh[0];
}

__global__ void scan2_kernel(int* __restrict__ bsum, int nb) {
    if (threadIdx.x == 0 && blockIdx.x == 0) {
        int run = 0;
        for (int i = 0; i < nb; ++i) { int v = bsum[i]; bsum[i] = run; run += v; }
    }
}

__global__ __launch_bounds__(256) void scan3_kernel(const int* __restrict__ cnt, const int* __restrict__ bsum,
                                                    int* __restrict__ offs, int* __restrict__ cursor) {
    __shared__ int sh[256];
    int b = blockIdx.x, t = threadIdx.x;
    int base = b * 1024 + t * 4;
    int v[4]; int s = 0;
#pragma unroll
    for (int j = 0; j < 4; ++j) { int i = base + j; v[j] = (i < NN) ? cnt[i] : 0; s += v[j]; }
    sh[t] = s; __syncthreads();
    for (int off = 1; off < 256; off <<= 1) {
        int x = (t >= off) ? sh[t - off] : 0; __syncthreads();
        sh[t] += x; __syncthreads();
    }
    int excl = sh[t] - s + bsum[b];
#pragma unroll
    for (int j = 0; j < 4; ++j) {
        int i = base + j;
        if (i < NN) { offs[i] = excl; cursor[i] = excl; excl += v[j]; }
    }
    if (b == 0 && t == 0) offs[NN] = NE;
}

// ---------------- CSR fill: src only (w recomputed in agg) ----------------
__global__ void csrfill_kernel(const int* __restrict__ ei,
                               int* __restrict__ cursor, int* __restrict__ csrc) {
    int stride = gridDim.x * blockDim.x;
    for (int e = blockIdx.x * blockDim.x + threadIdx.x; e < NE; e += stride) {
        int s = ei[e];
        int d = ei[NE + e];
        int p = atomicAdd(&cursor[d], 1);
        csrc[p] = s;
    }
}

// ---------------- MFMA GEMM: out[N,128](bf16) = A[N,128](bf16) @ Wc ----------------
__global__ __launch_bounds__(256) void gemm_mfma_kernel(const unsigned short* __restrict__ A,
                                                        const unsigned short* __restrict__ Wp,
                                                        unsigned short* __restrict__ out,
                                                        int nrows) {
    int w = threadIdx.x >> 6;
    int l = threadIdx.x & 63;
    int m0 = blockIdx.x * 64 + w * 16;
    int kg = l >> 4;            // 0..3
    int cl = l & 15;            // A row / C col within 16-group
    int arow = m0 + cl;

    short8 a[4];
    if (arow < nrows) {
        const short8* Ar = (const short8*)(A + (size_t)arow * HH);
#pragma unroll
        for (int kb = 0; kb < 4; ++kb) a[kb] = Ar[kb * 4 + kg];
    } else {
        short8 z = {};
#pragma unroll
        for (int kb = 0; kb < 4; ++kb) a[kb] = z;
    }

#pragma unroll
    for (int cb = 0; cb < 8; ++cb) {
        f32x4 acc = {0.f, 0.f, 0.f, 0.f};
#pragma unroll
        for (int kb = 0; kb < 4; ++kb) {
            short8 b = *(const short8*)(Wp + (size_t)(cb * 4 + kb) * 512 + l * 8);
            acc = __builtin_amdgcn_mfma_f32_16x16x32_bf16(a[kb], b, acc, 0, 0, 0);
        }
#pragma unroll
        for (int r = 0; r < 4; ++r) {
            int orow = m0 + kg * 4 + r;
            if (orow < nrows) out[(size_t)orow * HH + cb * 16 + cl] = f2bf(acc[r]);
        }
    }
}

// ---------- aggregation + self + bias + relu (bf16 rows, 16 lanes/node) ----------
// w = dinv[src]*dinv[dst] computed inline; dinv[s] (L2-resident) loads in
// parallel with the dependent row gather, so it's off the critical path.
__global__ __launch_bounds__(256) void agg_relu_kernel(const unsigned short* __restrict__ hT,
                                                       const int* __restrict__ offs,
                                                       const int* __restrict__ csrc,
                                                       const float* __restrict__ dinv,
                                                       const float* __restrict__ selfn,
                                                       const float* __restrict__ bias,
                                                       unsigned short* __restrict__ hOut) {
    int n = blockIdx.x * 16 + (threadIdx.x >> 4);
    if (n >= NN) return;
    int lane = threadIdx.x & 15;          // features lane*8 .. lane*8+7
    int beg = offs[n], end = offs[n + 1];
    const ushort8* h8 = (const ushort8*)hT;
    float dn = dinv[n];
    float acc[8] = {};
    int e = beg;
    for (; e + 3 < end; e += 4) {
        int s0 = csrc[e], s1 = csrc[e + 1], s2 = csrc[e + 2], s3 = csrc[e + 3];
        float w0 = dinv[s0] * dn, w1 = dinv[s1] * dn;
        float w2 = dinv[s2] * dn, w3 = dinv[s3] * dn;
        ushort8 v0 = h8[(size_t)s0 * 16 + lane];
        ushort8 v1 = h8[(size_t)s1 * 16 + lane];
        ushort8 v2 = h8[(size_t)s2 * 16 + lane];
        ushort8 v3 = h8[(size_t)s3 * 16 + lane];
#pragma unroll
        for (int j = 0; j < 8; ++j) {
            acc[j] = fmaf(bf2f(v0[j]), w0, acc[j]);
            acc[j] = fmaf(bf2f(v1[j]), w1, acc[j]);
            acc[j] = fmaf(bf2f(v2[j]), w2, acc[j]);
            acc[j] = fmaf(bf2f(v3[j]), w3, acc[j]);
        }
    }
    for (; e < end; ++e) {
        int s = csrc[e];
        float w = dinv[s] * dn;
        ushort8 v = h8[(size_t)s * 16 + lane];
#pragma unroll
        for (int j = 0; j < 8; ++j) acc[j] = fmaf(bf2f(v[j]), w, acc[j]);
    }
    float sn = selfn[n];
    ushort8 hv = h8[(size_t)n * 16 + lane];
    float4 bv0 = ((const float4*)bias)[lane * 2];
    float4 bv1 = ((const float4*)bias)[lane * 2 + 1];
    float bb[8] = {bv0.x, bv0.y, bv0.z, bv0.w, bv1.x, bv1.y, bv1.z, bv1.w};
    ushort8 o;
#pragma unroll
    for (int j = 0; j < 8; ++j) {
        float v = fmaxf(acc[j] + bf2f(hv[j]) * sn + bb[j], 0.f);
        o[j] = f2bf(v);
    }
    ((ushort8*)hOut)[(size_t)n * 16 + lane] = o;
}

// ---------------- pooling: counts via binary search (batch is sorted) ----------------
__global__ void poolcnt_bs_kernel(const int* __restrict__ batch, int* __restrict__ pcnt) {
    int g = threadIdx.x;
    if (g >= GG) return;
    int lo = 0, hi = NN;
    while (lo < hi) { int mid = (lo + hi) >> 1; if (batch[mid] < g) lo = mid + 1; else hi = mid; }
    int lb = lo;
    lo = 0; hi = NN;
    while (lo < hi) { int mid = (lo + hi) >> 1; if (batch[mid] <= g) lo = mid + 1; else hi = mid; }
    pcnt[g] = lo - lb;
}

__global__ __launch_bounds__(128) void poolsum_kernel(const unsigned short* __restrict__ h,
                                                      const int* __restrict__ batch,
                                                      float* __restrict__ psum) {
    const int CH = 256;
    int start = blockIdx.x * CH;
    if (start >= NN) return;
    int endn = min(start + CH, NN);
    int t = threadIdx.x;
    int curg = batch[start];
    float acc = 0.f;
    for (int n = start; n < endn; ++n) {
        int g = batch[n];
        if (g != curg) { atomicAdd(&psum[curg * HH + t], acc); acc = 0.f; curg = g; }
        acc += bf2f(h[(size_t)n * HH + t]);
    }
    atomicAdd(&psum[curg * HH + t], acc);
}

// ---------------- readout MLP + log_softmax ----------------
__global__ __launch_bounds__(128) void mlp_kernel(const float* __restrict__ psum,
                                                  const int* __restrict__ pcnt,
                                                  const float* __restrict__ Wl1,
                                                  const float* __restrict__ bl1,
                                                  const float* __restrict__ Wl2,
                                                  const float* __restrict__ bl2,
                                                  float* __restrict__ out) {
    __shared__ float p[128], o1[128], lg[CC];
    int g = blockIdx.x, t = threadIdx.x;
    float cnt = fmaxf((float)pcnt[g], 1.0f);
    p[t] = psum[g * HH + t] / cnt;
    __syncthreads();
    float acc = bl1[t];
    for (int k = 0; k < HH; ++k) acc = fmaf(p[k], Wl1[k * HH + t], acc);
    o1[t] = fmaxf(acc, 0.f);
    __syncthreads();
    if (t < CC) {
        float a2 = bl2[t];
        for (int j = 0; j < HH; ++j) a2 = fmaf(o1[j], Wl2[j * CC + t], a2);
        lg[t] = a2;
    }
    __syncthreads();
    if (t == 0) {
        float m = lg[0];
        for (int c = 1; c < CC; ++c) m = fmaxf(m, lg[c]);
        float s = 0.f;
        for (int c = 0; c < CC; ++c) s += expf(lg[c] - m);
        float ls = logf(s);
        for (int c = 0; c < CC; ++c) out[g * CC + c] = lg[c] - m - ls;
    }
}

extern "C" void kernel_launch(void* const* d_in, const int* in_sizes, int n_in,
                              void* d_out, int out_size, void* d_ws, size_t ws_size,
                              hipStream_t stream) {
    const float* x   = (const float*)d_in[0];
    const int*   ei  = (const int*)d_in[1];
    const int*   bat = (const int*)d_in[2];
    const float* W1  = (const float*)d_in[3];
    const float* b1  = (const float*)d_in[4];
    const float* Wr1 = (const float*)d_in[5];
    const float* br1 = (const float*)d_in[6];
    const float* W2  = (const float*)d_in[7];
    const float* b2  = (const float*)d_in[8];
    const float* Wr  = (const float*)d_in[9];
    const float* br  = (const float*)d_in[10];
    const float* Wl1 = (const float*)d_in[11];
    const float* bl1 = (const float*)d_in[12];
    const float* Wl2 = (const float*)d_in[13];
    const float* bl2 = (const float*)d_in[14];
    float* out = (float*)d_out;

    // workspace carve-up (256B aligned)
    char* base = (char*)d_ws;
    size_t off = 0;
    auto alloc = [&](size_t bytes) {
        void* p = base + off;
        off += (bytes + 255) & ~(size_t)255;
        return p;
    };
    unsigned short* xb   = (unsigned short*)alloc((size_t)NN * HH * 2);
    unsigned short* bufT = (unsigned short*)alloc((size_t)NN * HH * 2);
    unsigned short* bufH = (unsigned short*)alloc((size_t)NN * HH * 2);
    int*   csrc   = (int*)alloc((size_t)NE * 4);
    int*   offs   = (int*)alloc((size_t)(NN + 1) * 4);
    int*   cursor = (int*)alloc((size_t)NN * 4);
    int*   cnt    = (int*)alloc((size_t)NN * 4);
    float* dinv   = (float*)alloc((size_t)NN * 4);
    float* selfn  = (float*)alloc((size_t)NN * 4);
    int*   bsum   = (int*)alloc(128 * 4);
    unsigned short* Wpack = (unsigned short*)alloc(3 * 16384 * 2);
    float* bc     = (float*)alloc(3 * HH * 4);
    float* psum   = (float*)alloc(GG * HH * 4);
    int*   pcnt   = (int*)alloc(GG * 4);
    (void)ws_size; (void)in_sizes; (void)n_in; (void)out_size;

    hipMemsetAsync(cnt, 0, (size_t)NN * 4, stream);
    hipMemsetAsync(psum, 0, (size_t)GG * HH * 4, stream);

    // input convert + combined packed weights
    f2bf_kernel<<<(NN * HH / 8 + 255) / 256, 256, 0, stream>>>(x, xb);
    combw_kernel<<<(3 * 16384 + 255) / 256, 256, 0, stream>>>(W1, b1, Wr1, br1, W2, b2, Wr, br, Wpack, bc);

    // graph preprocessing
    hist_kernel<<<2048, 256, 0, stream>>>(ei, cnt);
    deg_kernel<<<512, 256, 0, stream>>>(cnt, dinv, selfn);
    const int NB = (NN + 1023) / 1024;  // 98
    scan1_kernel<<<NB, 256, 0, stream>>>(cnt, bsum);
    scan2_kernel<<<1, 64, 0, stream>>>(bsum, NB);
    scan3_kernel<<<NB, 256, 0, stream>>>(cnt, bsum, offs, cursor);
    csrfill_kernel<<<2048, 256, 0, stream>>>(ei, cursor, csrc);

    const int GEMM_BLOCKS = (NN + 63) / 64;
    const int AGG_BLOCKS = (NN + 15) / 16;
    // layer 0
    gemm_mfma_kernel<<<GEMM_BLOCKS, 256, 0, stream>>>(xb, Wpack, bufT, NN);
    agg_relu_kernel<<<AGG_BLOCKS, 256, 0, stream>>>(bufT, offs, csrc, dinv, selfn, bc, bufH);
    // layer 1
    gemm_mfma_kernel<<<GEMM_BLOCKS, 256, 0, stream>>>(bufH, Wpack + 16384, bufT, NN);
    agg_relu_kernel<<<AGG_BLOCKS, 256, 0, stream>>>(bufT, offs, csrc, dinv, selfn, bc + HH, bufH);
    // layer 2
    gemm_mfma_kernel<<<GEMM_BLOCKS, 256, 0, stream>>>(bufH, Wpack + 2 * 16384, bufT, NN);
    agg_relu_kernel<<<AGG_BLOCKS, 256, 0, stream>>>(bufT, offs, csrc, dinv, selfn, bc + 2 * HH, bufH);

    // pooling + readout
    poolcnt_bs_kernel<<<1, 64, 0, stream>>>(bat, pcnt);
    poolsum_kernel<<<(NN + 255) / 256, 128, 0, stream>>>(bufH, bat, psum);
    mlp_kernel<<<GG, 128, 0, stream>>>(psum, pcnt, Wl1, bl1, Wl2, bl2, out);
}

// Round 5
// 505.071 us; speedup vs baseline: 1.1308x; 1.1308x over previous
//
#include <hip/hip_runtime.h>
#include <hip/hip_bf16.h>

#define NN 100000
#define NE 1600000
#define FF 128
#define HH 128
#define CC 10
#define GG 64
#define NRANGE 8
#define RSPAN (NN / NRANGE)   // 12500

typedef __attribute__((ext_vector_type(8))) short short8;
typedef __attribute__((ext_vector_type(8))) unsigned short ushort8;
typedef __attribute__((ext_vector_type(4))) float f32x4;

__device__ inline float bf2f(unsigned short u) {
    union { unsigned int i; float f; } x;
    x.i = ((unsigned int)u) << 16;
    return x.f;
}
__device__ inline unsigned short f2bf(float f) {
    union { float f; unsigned int i; } x;
    x.f = f;
    unsigned int r = x.i + 0x7FFF + ((x.i >> 16) & 1);  // RNE
    return (unsigned short)(r >> 16);
}

// ---------------- f32 -> bf16 bulk convert (8 elems/thread) ----------------
__global__ __launch_bounds__(256) void f2bf_kernel(const float* __restrict__ x,
                                                   unsigned short* __restrict__ xb) {
    int i = blockIdx.x * blockDim.x + threadIdx.x;
    if (i >= NN * HH / 8) return;
    float4 v0 = ((const float4*)x)[i * 2];
    float4 v1 = ((const float4*)x)[i * 2 + 1];
    ushort8 o;
    o[0] = f2bf(v0.x); o[1] = f2bf(v0.y); o[2] = f2bf(v0.z); o[3] = f2bf(v0.w);
    o[4] = f2bf(v1.x); o[5] = f2bf(v1.y); o[6] = f2bf(v1.z); o[7] = f2bf(v1.w);
    ((ushort8*)xb)[i] = o;
}

// ---------------- weight combine + pack into MFMA B-fragment order (bf16) ----
__global__ void combw_kernel(const float* __restrict__ W1, const float* __restrict__ b1,
                             const float* __restrict__ Wr1, const float* __restrict__ br1,
                             const float* __restrict__ W2, const float* __restrict__ b2,
                             const float* __restrict__ Wr, const float* __restrict__ br,
                             unsigned short* __restrict__ Wpack, float* __restrict__ bc) {
    int idx = blockIdx.x * blockDim.x + threadIdx.x;
    if (idx >= 3 * 16384) return;
    int l = idx / 16384, rem = idx % 16384;
    int cb = rem / 2048;
    int kb = (rem / 512) % 4;
    int lane = (rem / 8) % 64;
    int j = rem % 8;
    int k = kb * 32 + (lane >> 4) * 8 + j;
    int c = cb * 16 + (lane & 15);
    int wi = k * HH + c;
    float v = (l == 0) ? 0.95f * W1[wi] + 0.05f * Wr1[wi]
                       : 0.95f * W2[(l - 1) * 16384 + wi] + 0.05f * Wr[wi];
    Wpack[idx] = f2bf(v);
    if (rem < HH) {
        bc[l * HH + rem] = (l == 0) ? 0.95f * b1[rem] + 0.05f * br1[rem]
                                    : 0.95f * b2[(l - 1) * HH + rem] + 0.05f * br[rem];
    }
}

// ------------- degree histogram over dst, dst-range binned (XCD-local) -------------
__global__ void hist_kernel(const int* __restrict__ ei, int* __restrict__ cnt) {
    int range = blockIdx.x & (NRANGE - 1);
    int lo = range * RSPAN, hi = lo + RSPAN;
    int tid = (blockIdx.x >> 3) * blockDim.x + threadIdx.x;
    int stride = (gridDim.x >> 3) * blockDim.x;
    for (int e = tid; e < NE; e += stride) {
        int d = ei[NE + e];
        if (d >= lo && d < hi) atomicAdd(&cnt[d], 1);
    }
}

__global__ void deg_kernel(const int* __restrict__ cnt, float* __restrict__ dinv,
                           float* __restrict__ selfn) {
    int stride = gridDim.x * blockDim.x;
    for (int n = blockIdx.x * blockDim.x + threadIdx.x; n < NN; n += stride) {
        float dg = (float)cnt[n] + 1.0f;
        dinv[n] = rsqrtf(dg);
        selfn[n] = 1.0f / dg;
    }
}

// ---------------- 3-kernel exclusive scan of cnt -> offs ----------------
__global__ __launch_bounds__(256) void scan1_kernel(const int* __restrict__ cnt, int* __restrict__ bsum) {
    __shared__ int sh[256];
    int b = blockIdx.x, t = threadIdx.x;
    int base = b * 1024 + t * 4;
    int s = 0;
#pragma unroll
    for (int j = 0; j < 4; ++j) { int i = base + j; if (i < NN) s += cnt[i]; }
    sh[t] = s; __syncthreads();
    for (int off = 128; off; off >>= 1) { if (t < off) sh[t] += sh[t + off]; __syncthreads(); }
    if (t == 0) bsum[b] = sh[0];
}

__global__ void scan2_kernel(int* __restrict__ bsum, int nb) {
    if (threadIdx.x == 0 && blockIdx.x == 0) {
        int run = 0;
        for (int i = 0; i < nb; ++i) { int v = bsum[i]; bsum[i] = run; run += v; }
    }
}

__global__ __launch_bounds__(256) void scan3_kernel(const int* __restrict__ cnt, const int* __restrict__ bsum,
                                                    int* __restrict__ offs, int* __restrict__ cursor) {
    __shared__ int sh[256];
    int b = blockIdx.x, t = threadIdx.x;
    int base = b * 1024 + t * 4;
    int v[4]; int s = 0;
#pragma unroll
    for (int j = 0; j < 4; ++j) { int i = base + j; v[j] = (i < NN) ? cnt[i] : 0; s += v[j]; }
    sh[t] = s; __syncthreads();
    for (int off = 1; off < 256; off <<= 1) {
        int x = (t >= off) ? sh[t - off] : 0; __syncthreads();
        sh[t] += x; __syncthreads();
    }
    int excl = sh[t] - s + bsum[b];
#pragma unroll
    for (int j = 0; j < 4; ++j) {
        int i = base + j;
        if (i < NN) { offs[i] = excl; cursor[i] = excl; excl += v[j]; }
    }
    if (b == 0 && t == 0) offs[NN] = NE;
}

// ------------- CSR fill (src + enorm), dst-range binned (XCD-local) -------------
__global__ void csrfill_kernel(const int* __restrict__ ei, const float* __restrict__ dinv,
                               int* __restrict__ cursor, int* __restrict__ csrc,
                               float* __restrict__ cw) {
    int range = blockIdx.x & (NRANGE - 1);
    int lo = range * RSPAN, hi = lo + RSPAN;
    int tid = (blockIdx.x >> 3) * blockDim.x + threadIdx.x;
    int stride = (gridDim.x >> 3) * blockDim.x;
    for (int e = tid; e < NE; e += stride) {
        int d = ei[NE + e];
        if (d >= lo && d < hi) {
            int s = ei[e];
            int p = atomicAdd(&cursor[d], 1);
            csrc[p] = s;
            cw[p] = dinv[s] * dinv[d];
        }
    }
}

// ---------------- MFMA GEMM: out[N,128](bf16) = A[N,128](bf16) @ Wc ----------------
__global__ __launch_bounds__(256) void gemm_mfma_kernel(const unsigned short* __restrict__ A,
                                                        const unsigned short* __restrict__ Wp,
                                                        unsigned short* __restrict__ out,
                                                        int nrows) {
    int w = threadIdx.x >> 6;
    int l = threadIdx.x & 63;
    int m0 = blockIdx.x * 64 + w * 16;
    int kg = l >> 4;            // 0..3
    int cl = l & 15;            // A row / C col within 16-group
    int arow = m0 + cl;

    short8 a[4];
    if (arow < nrows) {
        const short8* Ar = (const short8*)(A + (size_t)arow * HH);
#pragma unroll
        for (int kb = 0; kb < 4; ++kb) a[kb] = Ar[kb * 4 + kg];
    } else {
        short8 z = {};
#pragma unroll
        for (int kb = 0; kb < 4; ++kb) a[kb] = z;
    }

#pragma unroll
    for (int cb = 0; cb < 8; ++cb) {
        f32x4 acc = {0.f, 0.f, 0.f, 0.f};
#pragma unroll
        for (int kb = 0; kb < 4; ++kb) {
            short8 b = *(const short8*)(Wp + (size_t)(cb * 4 + kb) * 512 + l * 8);
            acc = __builtin_amdgcn_mfma_f32_16x16x32_bf16(a[kb], b, acc, 0, 0, 0);
        }
#pragma unroll
        for (int r = 0; r < 4; ++r) {
            int orow = m0 + kg * 4 + r;
            if (orow < nrows) out[(size_t)orow * HH + cb * 16 + cl] = f2bf(acc[r]);
        }
    }
}

// ---------- aggregation + self + bias + relu (bf16 rows, 16 lanes/node) ----------
__global__ __launch_bounds__(256) void agg_relu_kernel(const unsigned short* __restrict__ hT,
                                                       const int* __restrict__ offs,
                                                       const int* __restrict__ csrc,
                                                       const float* __restrict__ cw,
                                                       const float* __restrict__ selfn,
                                                       const float* __restrict__ bias,
                                                       unsigned short* __restrict__ hOut) {
    int n = blockIdx.x * 16 + (threadIdx.x >> 4);
    if (n >= NN) return;
    int lane = threadIdx.x & 15;          // features lane*8 .. lane*8+7
    int beg = offs[n], end = offs[n + 1];
    const ushort8* h8 = (const ushort8*)hT;
    float acc[8] = {};
    int e = beg;
    for (; e + 3 < end; e += 4) {
        int s0 = csrc[e], s1 = csrc[e + 1], s2 = csrc[e + 2], s3 = csrc[e + 3];
        float w0 = cw[e], w1 = cw[e + 1], w2 = cw[e + 2], w3 = cw[e + 3];
        ushort8 v0 = h8[(size_t)s0 * 16 + lane];
        ushort8 v1 = h8[(size_t)s1 * 16 + lane];
        ushort8 v2 = h8[(size_t)s2 * 16 + lane];
        ushort8 v3 = h8[(size_t)s3 * 16 + lane];
#pragma unroll
        for (int j = 0; j < 8; ++j) {
            acc[j] = fmaf(bf2f(v0[j]), w0, acc[j]);
            acc[j] = fmaf(bf2f(v1[j]), w1, acc[j]);
            acc[j] = fmaf(bf2f(v2[j]), w2, acc[j]);
            acc[j] = fmaf(bf2f(v3[j]), w3, acc[j]);
        }
    }
    for (; e < end; ++e) {
        int s = csrc[e];
        float w = cw[e];
        ushort8 v = h8[(size_t)s * 16 + lane];
#pragma unroll
        for (int j = 0; j < 8; ++j) acc[j] = fmaf(bf2f(v[j]), w, acc[j]);
    }
    float sn = selfn[n];
    ushort8 hv = h8[(size_t)n * 16 + lane];
    float4 bv0 = ((const float4*)bias)[lane * 2];
    float4 bv1 = ((const float4*)bias)[lane * 2 + 1];
    float bb[8] = {bv0.x, bv0.y, bv0.z, bv0.w, bv1.x, bv1.y, bv1.z, bv1.w};
    ushort8 o;
#pragma unroll
    for (int j = 0; j < 8; ++j) {
        float v = fmaxf(acc[j] + bf2f(hv[j]) * sn + bb[j], 0.f);
        o[j] = f2bf(v);
    }
    ((ushort8*)hOut)[(size_t)n * 16 + lane] = o;
}

// ---------------- pooling: counts via binary search (batch is sorted) ----------------
__global__ void poolcnt_bs_kernel(const int* __restrict__ batch, int* __restrict__ pcnt) {
    int g = threadIdx.x;
    if (g >= GG) return;
    int lo = 0, hi = NN;
    while (lo < hi) { int mid = (lo + hi) >> 1; if (batch[mid] < g) lo = mid + 1; else hi = mid; }
    int lb = lo;
    lo = 0; hi = NN;
    while (lo < hi) { int mid = (lo + hi) >> 1; if (batch[mid] <= g) lo = mid + 1; else hi = mid; }
    pcnt[g] = lo - lb;
}

__global__ __launch_bounds__(128) void poolsum_kernel(const unsigned short* __restrict__ h,
                                                      const int* __restrict__ batch,
                                                      float* __restrict__ psum) {
    const int CH = 256;
    int start = blockIdx.x * CH;
    if (start >= NN) return;
    int endn = min(start + CH, NN);
    int t = threadIdx.x;
    int curg = batch[start];
    float acc = 0.f;
    for (int n = start; n < endn; ++n) {
        int g = batch[n];
        if (g != curg) { atomicAdd(&psum[curg * HH + t], acc); acc = 0.f; curg = g; }
        acc += bf2f(h[(size_t)n * HH + t]);
    }
    atomicAdd(&psum[curg * HH + t], acc);
}

// ---------------- readout MLP + log_softmax ----------------
__global__ __launch_bounds__(128) void mlp_kernel(const float* __restrict__ psum,
                                                  const int* __restrict__ pcnt,
                                                  const float* __restrict__ Wl1,
                                                  const float* __restrict__ bl1,
                                                  const float* __restrict__ Wl2,
                                                  const float* __restrict__ bl2,
                                                  float* __restrict__ out) {
    __shared__ float p[128], o1[128], lg[CC];
    int g = blockIdx.x, t = threadIdx.x;
    float cnt = fmaxf((float)pcnt[g], 1.0f);
    p[t] = psum[g * HH + t] / cnt;
    __syncthreads();
    float acc = bl1[t];
    for (int k = 0; k < HH; ++k) acc = fmaf(p[k], Wl1[k * HH + t], acc);
    o1[t] = fmaxf(acc, 0.f);
    __syncthreads();
    if (t < CC) {
        float a2 = bl2[t];
        for (int j = 0; j < HH; ++j) a2 = fmaf(o1[j], Wl2[j * CC + t], a2);
        lg[t] = a2;
    }
    __syncthreads();
    if (t == 0) {
        float m = lg[0];
        for (int c = 1; c < CC; ++c) m = fmaxf(m, lg[c]);
        float s = 0.f;
        for (int c = 0; c < CC; ++c) s += expf(lg[c] - m);
        float ls = logf(s);
        for (int c = 0; c < CC; ++c) out[g * CC + c] = lg[c] - m - ls;
    }
}

extern "C" void kernel_launch(void* const* d_in, const int* in_sizes, int n_in,
                              void* d_out, int out_size, void* d_ws, size_t ws_size,
                              hipStream_t stream) {
    const float* x   = (const float*)d_in[0];
    const int*   ei  = (const int*)d_in[1];
    const int*   bat = (const int*)d_in[2];
    const float* W1  = (const float*)d_in[3];
    const float* b1  = (const float*)d_in[4];
    const float* Wr1 = (const float*)d_in[5];
    const float* br1 = (const float*)d_in[6];
    const float* W2  = (const float*)d_in[7];
    const float* b2  = (const float*)d_in[8];
    const float* Wr  = (const float*)d_in[9];
    const float* br  = (const float*)d_in[10];
    const float* Wl1 = (const float*)d_in[11];
    const float* bl1 = (const float*)d_in[12];
    const float* Wl2 = (const float*)d_in[13];
    const float* bl2 = (const float*)d_in[14];
    float* out = (float*)d_out;

    // workspace carve-up (256B aligned)
    char* base = (char*)d_ws;
    size_t off = 0;
    auto alloc = [&](size_t bytes) {
        void* p = base + off;
        off += (bytes + 255) & ~(size_t)255;
        return p;
    };
    unsigned short* xb   = (unsigned short*)alloc((size_t)NN * HH * 2);
    unsigned short* bufT = (unsigned short*)alloc((size_t)NN * HH * 2);
    unsigned short* bufH = (unsigned short*)alloc((size_t)NN * HH * 2);
    int*   csrc   = (int*)alloc((size_t)NE * 4);
    float* cw     = (float*)alloc((size_t)NE * 4);
    int*   offs   = (int*)alloc((size_t)(NN + 1) * 4);
    int*   cursor = (int*)alloc((size_t)NN * 4);
    int*   cnt    = (int*)alloc((size_t)NN * 4);
    float* dinv   = (float*)alloc((size_t)NN * 4);
    float* selfn  = (float*)alloc((size_t)NN * 4);
    int*   bsum   = (int*)alloc(128 * 4);
    unsigned short* Wpack = (unsigned short*)alloc(3 * 16384 * 2);
    float* bc     = (float*)alloc(3 * HH * 4);
    float* psum   = (float*)alloc(GG * HH * 4);
    int*   pcnt   = (int*)alloc(GG * 4);
    (void)ws_size; (void)in_sizes; (void)n_in; (void)out_size;

    hipMemsetAsync(cnt, 0, (size_t)NN * 4, stream);
    hipMemsetAsync(psum, 0, (size_t)GG * HH * 4, stream);

    // input convert + combined packed weights
    f2bf_kernel<<<(NN * HH / 8 + 255) / 256, 256, 0, stream>>>(x, xb);
    combw_kernel<<<(3 * 16384 + 255) / 256, 256, 0, stream>>>(W1, b1, Wr1, br1, W2, b2, Wr, br, Wpack, bc);

    // graph preprocessing (hist/csrfill are dst-range binned for XCD-local atomics)
    hist_kernel<<<8 * 256, 256, 0, stream>>>(ei, cnt);
    deg_kernel<<<512, 256, 0, stream>>>(cnt, dinv, selfn);
    const int NB = (NN + 1023) / 1024;  // 98
    scan1_kernel<<<NB, 256, 0, stream>>>(cnt, bsum);
    scan2_kernel<<<1, 64, 0, stream>>>(bsum, NB);
    scan3_kernel<<<NB, 256, 0, stream>>>(cnt, bsum, offs, cursor);
    csrfill_kernel<<<8 * 256, 256, 0, stream>>>(ei, dinv, cursor, csrc, cw);

    const int GEMM_BLOCKS = (NN + 63) / 64;
    const int AGG_BLOCKS = (NN + 15) / 16;
    // layer 0
    gemm_mfma_kernel<<<GEMM_BLOCKS, 256, 0, stream>>>(xb, Wpack, bufT, NN);
    agg_relu_kernel<<<AGG_BLOCKS, 256, 0, stream>>>(bufT, offs, csrc, cw, selfn, bc, bufH);
    // layer 1
    gemm_mfma_kernel<<<GEMM_BLOCKS, 256, 0, stream>>>(bufH, Wpack + 16384, bufT, NN);
    agg_relu_kernel<<<AGG_BLOCKS, 256, 0, stream>>>(bufT, offs, csrc, cw, selfn, bc + HH, bufH);
    // layer 2
    gemm_mfma_kernel<<<GEMM_BLOCKS, 256, 0, stream>>>(bufH, Wpack + 2 * 16384, bufT, NN);
    agg_relu_kernel<<<AGG_BLOCKS, 256, 0, stream>>>(bufT, offs, csrc, cw, selfn, bc + 2 * HH, bufH);

    // pooling + readout
    poolcnt_bs_kernel<<<1, 64, 0, stream>>>(bat, pcnt);
    poolsum_kernel<<<(NN + 255) / 256, 128, 0, stream>>>(bufH, bat, psum);
    mlp_kernel<<<GG, 128, 0, stream>>>(psum, pcnt, Wl1, bl1, Wl2, bl2, out);
}